// Round 14
// baseline (555.686 us; speedup 1.0000x reference)
//
#include <hip/hip_runtime.h>

using short8 = __attribute__((ext_vector_type(8))) short;
using bf16x8 = __attribute__((ext_vector_type(8))) __bf16;
using f32x4  = __attribute__((ext_vector_type(4))) float;

__device__ __forceinline__ void gload_lds16(const void* g, void* l) {
  __builtin_amdgcn_global_load_lds(
      (const __attribute__((address_space(1))) void*)g,
      (__attribute__((address_space(3))) void*)l, 16, 0, 0);
}

// ---------------- prepass: decode/convert ----------------

__device__ __forceinline__ float dec_e4m3(int b) {
  int e = (b >> 3) & 15;
  int m = b & 7;
  if (e == 15 && m == 7) m = 6;  // NaN pattern -> 448 per reference
  float v;
  if (e) v = (1.0f + (float)m * 0.125f) * __uint_as_float((unsigned)(e + 120) << 23);
  else   v = (float)m * 0.001953125f;  // m * 2^-9
  return (b & 0x80) ? -v : v;
}

__global__ void dec_w_kernel(const int* __restrict__ wq,
                             unsigned short* __restrict__ wb, int n8) {
  int i = blockIdx.x * blockDim.x + threadIdx.x;
  if (i >= n8) return;
  const int4* p = (const int4*)wq + (size_t)i * 2;
  int4 a = p[0], b4 = p[1];
  int bv[8] = {a.x, a.y, a.z, a.w, b4.x, b4.y, b4.z, b4.w};
  short8 r;
#pragma unroll
  for (int j = 0; j < 8; ++j) {
    float f = dec_e4m3(bv[j]);
    r[j] = (short)(__float_as_uint(f) >> 16);  // exact (<=3 mantissa bits)
  }
  *(short8*)(wb + (size_t)i * 8) = r;
}

__global__ void cvt_x_kernel(const float* __restrict__ x,
                             unsigned short* __restrict__ xb, int n8) {
  int i = blockIdx.x * blockDim.x + threadIdx.x;
  if (i >= n8) return;
  const float4* p = (const float4*)x + (size_t)i * 2;
  float4 a = p[0], b4 = p[1];
  float v[8] = {a.x, a.y, a.z, a.w, b4.x, b4.y, b4.z, b4.w};
  short8 r;
#pragma unroll
  for (int j = 0; j < 8; ++j) {
    unsigned u = __float_as_uint(v[j]);
    u += 0x7FFFu + ((u >> 16) & 1u);  // RNE
    r[j] = (short)(u >> 16);
  }
  *(short8*)(xb + (size_t)i * 8) = r;
}

// ------- 256x256 GEMM: 2 merged phases/tile (4 barriers / 2 tiles) --------
// C[t,o] = scale[o] * sum_k A[t,k]*B[o,k] + bias[o]
// A: [T][K] bf16, B: [N][K] bf16 (row-major, B^T GEMM). 512 thr = 8 waves
// (2M x 4N), per-wave C 128x64 = acc[8][4] 16x16 f32x4. LDS 128KB dbuf.
// XOR swizzle byte^=((row&7)<<4) via pre-swizzled global source (0-conflict).
// R14: R13's stage/VM/prefetch ISSUE ORDER preserved exactly; only the
// barrier count halves (phase pairs merged -> 32-MFMA clusters, 2 phases
// per tile). PhA: {MFMA (0,0)+(0,1); stages; prefetch aO}. PhB: {MFMA
// (1,1)+(1,0); stages; VM6; prefetch next tile's aE,b0,b1}. All waits
// strictly after the cluster (R9/R10 lesson), no branches in body (R12).
// B half1 gets a parity bank (b1a/b1b). Hazard audit: every prefetched
// region's overwriting stage is issued >=1 cluster after the read, +200cyc
// DMA return margin; VM6 queue sim drains exactly the consumed buffer.
// Chains of 4 bm tiles; XCD-column locality map; NT-store epilogue.

#define NOPV ((void)0)
#define VM6 asm volatile("s_waitcnt vmcnt(6)" ::: "memory")
#define VM0 asm volatile("s_waitcnt vmcnt(0)" ::: "memory")

#define STAGE_A(GP, LBUF, KT, J) do { \
    const char* _g = (GP) + (size_t)(KT) * 128u; \
    gload_lds16(_g + (size_t)((J) * 64) * Kb, (LBUF) + ((J) * 64) * 128 + tdA); \
    gload_lds16(_g + (size_t)(128 + (J) * 64) * Kb, (LBUF) + (128 + (J) * 64) * 128 + tdA); \
  } while (0)

#define STAGE_B(GP, LBUF, KT, J) do { \
    const char* _g = (GP) + (size_t)(KT) * 128u; \
    gload_lds16(_g + (size_t)((J) * 32) * Kb, (LBUF) + ((J) * 32) * 128 + tdB); \
    gload_lds16(_g + (size_t)(128 + (J) * 32) * Kb, (LBUF) + (128 + (J) * 32) * 128 + tdB); \
  } while (0)

// A-quadrant QM from LDS byte-base LB: 8 x ds_read_b128 (0-conflict layout)
#define RD_A(DST, LB, QM) do { \
    _Pragma("unroll") \
    for (int mi = 0; mi < 4; ++mi) { \
      const char* _b = lds + (LB) + (size_t)(arow + (QM) * 64 + mi * 16) * 128; \
      (DST)[mi * 2 + 0] = *(const bf16x8*)(_b + fo0); \
      (DST)[mi * 2 + 1] = *(const bf16x8*)(_b + fo1); \
    } \
  } while (0)

// B-half QN from LDS byte-base LB: 4 x ds_read_b128
#define RD_B(DST, LB, QN) do { \
    _Pragma("unroll") \
    for (int ni = 0; ni < 2; ++ni) { \
      const char* _b = lds + (LB) + 32768 + (size_t)(brow + ((QN) * 2 + ni) * 16) * 128; \
      (DST)[ni * 2 + 0] = *(const bf16x8*)(_b + fo0); \
      (DST)[ni * 2 + 1] = *(const bf16x8*)(_b + fo1); \
    } \
  } while (0)

#define MF16(AB, BB, QM, QN) \
    _Pragma("unroll") \
    for (int mi = 0; mi < 4; ++mi) \
      _Pragma("unroll") \
      for (int ni = 0; ni < 2; ++ni) \
        _Pragma("unroll") \
        for (int ks = 0; ks < 2; ++ks) \
          acc[(QM) * 4 + mi][(QN) * 2 + ni] = __builtin_amdgcn_mfma_f32_16x16x32_bf16( \
              (AB)[mi * 2 + ks], (BB)[ni * 2 + ks], acc[(QM) * 4 + mi][(QN) * 2 + ni], 0, 0, 0);

// Merged phase: 32 MFMAs (2 quadrant-pairs); compiler scoreboards the
// lgkm deps of last phase's prefetch (fine-grained waits inside cluster).
#define PH2(AB1, BB1, QM1, QN1, AB2, BB2, QM2, QN2, STBLK, VMBLK, PFBLK) do { \
    __builtin_amdgcn_s_setprio(1); \
    MF16(AB1, BB1, QM1, QN1) \
    MF16(AB2, BB2, QM2, QN2) \
    __builtin_amdgcn_s_setprio(0); \
    __builtin_amdgcn_sched_barrier(0); \
    STBLK; \
    VMBLK; \
    PFBLK; \
    __builtin_amdgcn_s_barrier(); \
  } while (0)

__global__ __launch_bounds__(512, 2) void gemm256_kernel(
    const unsigned short* __restrict__ A, const unsigned short* __restrict__ B,
    const float* __restrict__ scale, const float* __restrict__ bias,
    float* __restrict__ out, int T, int K, int N) {
  extern __shared__ char lds[];
  char* const lA0 = lds;
  char* const lB0 = lds + 32768;
  char* const lA1 = lds + 65536;
  char* const lB1 = lds + 98304;
  const int L0A = 0, L0B = 0, L1A = 65536, L1B = 65536;  // RD_* add +32768 for B

  const int nbn = N >> 8;
  const int nbm = T >> 8;
  int bm, bn, CH;
  if (((nbm & 3) == 0) && ((nbn & 7) == 0) &&
      (int)gridDim.x == (nbm >> 2) * nbn) {
    const int xcd = blockIdx.x & 7, off = blockIdx.x >> 3;
    const int cpx = nbn >> 3;
    const int col = xcd * cpx + (off % cpx);
    const int ci  = off / cpx;
    bm = (ci * 4) << 8;
    bn = col << 8;
    CH = 4;
  } else {
    const int nwg = nbm * nbn;
    const int q = nwg >> 3, r = nwg & 7;
    const int xcd = blockIdx.x & 7, off = blockIdx.x >> 3;
    const int swz = (xcd < r ? xcd * (q + 1) : r * (q + 1) + (xcd - r) * q) + off;
    bm = (swz / nbn) << 8;
    bn = (swz % nbn) << 8;
    CH = 1;
  }

  const int tid = threadIdx.x;
  const int wave = tid >> 6, lane = tid & 63;
  const int wm = wave >> 2, wn = wave & 3;
  const int nt = K >> 6;           // K-tiles (BK=64); requires nt even >= 4
  const size_t Kb = (size_t)K * 2;

  // staging (pre-swizzled global source, linear LDS dest) — R2-verified
  const int trow = tid >> 3;
  const int gcol = ((tid & 7) * 16) ^ (((tid >> 3) & 7) << 4);
  const int bmap = ((tid & 256) ? 64 : 0) + ((tid >> 6) & 3) * 8 + ((tid >> 3) & 7);
  const char* gAb = (const char*)A + (size_t)(bm + trow) * Kb + gcol;
  const char* gBb = (const char*)B + (size_t)(bn + bmap) * Kb + gcol;
  const int tdA = tid * 16;
  const int tdB = bmap * 128 + (tid & 7) * 16;

  // fragment read offsets (0-conflict, R2)
  const int g16 = lane >> 4, l8 = lane & 7;
  const int fo0 = ((g16 ^ l8) << 4);
  const int fo1 = fo0 ^ 64;
  const int arow = wm * 128 + (lane & 15);
  const int brow = wn * 64 + (lane & 15);

  // epilogue addressing + hoisted scale/bias (bn fixed for whole chain)
  const int ccol = bn + wn * 64 + (lane & 15);
  int crow = bm + wm * 128 + ((lane >> 4) << 2);
  float scv[4], biv[4];
#pragma unroll
  for (int ni = 0; ni < 4; ++ni) {
    scv[ni] = scale[ccol + ni * 16];
    biv[ni] = bias[ccol + ni * 16];
  }

  f32x4 acc[8][4] = {};
  bf16x8 aE[8], aO[8], b0a[4], b0b[4], b1a[4], b1b[4];

  for (int ch = 0; ch < CH; ++ch) {
    const bool more = (ch + 1 < CH);
    const char* gAn = gAb + (size_t)256 * Kb;

    if (ch == 0) {
      // cold prologue: tile0 full (8), tile1 {Ah0,Bh0,Bh1} (6); VM6 -> tile0 ready
      STAGE_A(gAb, lA0, 0, 0);
      STAGE_B(gBb, lB0, 0, 0);
      STAGE_B(gBb, lB0, 0, 1);
      STAGE_A(gAb, lA0, 0, 1);
      STAGE_A(gAb, lA1, 1, 0);
      STAGE_B(gBb, lB1, 1, 0);
      STAGE_B(gBb, lB1, 1, 1);
      VM6;
      __builtin_amdgcn_s_barrier();
      RD_A(aE, L0A, 0);
      RD_B(b0a, L0B, 0);
      RD_B(b1a, L0B, 1);
    }

    int t = 0;
    for (; t + 3 < nt; t += 2) {
      // tile t (buf0): banks aE,aO,b0a,b1a
      PH2(aE, b0a, 0, 0, aE, b1a, 0, 1,
          { STAGE_A(gAb, lA1, t + 1, 1); STAGE_A(gAb, lA0, t + 2, 0); },
          NOPV, RD_A(aO, L0A, 1));
      PH2(aO, b1a, 1, 1, aO, b0a, 1, 0,
          { STAGE_B(gBb, lB0, t + 2, 0); STAGE_B(gBb, lB0, t + 2, 1); },
          VM6, { RD_A(aE, L1A, 0); RD_B(b0b, L1B, 0); RD_B(b1b, L1B, 1); });
      // tile t+1 (buf1): banks aE,aO,b0b,b1b
      PH2(aE, b0b, 0, 0, aE, b1b, 0, 1,
          { STAGE_A(gAb, lA0, t + 2, 1); STAGE_A(gAb, lA1, t + 3, 0); },
          NOPV, RD_A(aO, L1A, 1));
      PH2(aO, b1b, 1, 1, aO, b0b, 1, 0,
          { STAGE_B(gBb, lB1, t + 3, 0); STAGE_B(gBb, lB1, t + 3, 1); },
          VM6, { RD_A(aE, L0A, 0); RD_B(b0a, L0B, 0); RD_B(b1a, L0B, 1); });
    }
    // tail: tile nt-2 (buf0); VM0 -> buf1 fully resident before its reads
    PH2(aE, b0a, 0, 0, aE, b1a, 0, 1,
        STAGE_A(gAb, lA1, t + 1, 1), NOPV, RD_A(aO, L0A, 1));
    PH2(aO, b1a, 1, 1, aO, b0a, 1, 0,
        NOPV, VM0, { RD_A(aE, L1A, 0); RD_B(b0b, L1B, 0); RD_B(b1b, L1B, 1); });
    // tail: tile nt-1 (buf1); weave next-chain k0 stages into buf0
    PH2(aE, b0b, 0, 0, aE, b1b, 0, 1,
        { if (more) { STAGE_A(gAn, lA0, 0, 0); STAGE_B(gBb, lB0, 0, 0); } },
        NOPV, RD_A(aO, L1A, 1));
    PH2(aO, b1b, 1, 1, aO, b0b, 1, 0,
        { if (more) { STAGE_B(gBb, lB0, 0, 1); STAGE_A(gAn, lA0, 0, 1); } },
        NOPV, NOPV);

    // epilogue: NT stores (C/D: col=lane&15, row=(lane>>4)*4+reg)
#pragma unroll
    for (int ni = 0; ni < 4; ++ni) {
      const int o = ccol + ni * 16;
#pragma unroll
      for (int mi = 0; mi < 8; ++mi) {
#pragma unroll
        for (int rr = 0; rr < 4; ++rr) {
          __builtin_nontemporal_store(acc[mi][ni][rr] * scv[ni] + biv[ni],
                                      &out[(size_t)(crow + mi * 16 + rr) * N + o]);
        }
      }
    }

    if (more) {
#pragma unroll
      for (int mi = 0; mi < 8; ++mi)
#pragma unroll
        for (int ni = 0; ni < 4; ++ni)
          acc[mi][ni] = (f32x4){0.f, 0.f, 0.f, 0.f};
      // stage next tile's k1; VM6 -> k0 landed; prefetch first operands
      STAGE_A(gAn, lA1, 1, 0);
      STAGE_B(gBb, lB1, 1, 0);
      STAGE_B(gBb, lB1, 1, 1);
      VM6;
      __builtin_amdgcn_s_barrier();
      RD_A(aE, L0A, 0);
      RD_B(b0a, L0B, 0);
      RD_B(b1a, L0B, 1);
      gAb = gAn;
      crow += 256;
    }
  }
}

// ---------------- m97 128x128 fallback ----------------

#define BM 128
#define BN 128
#define BK 64

__global__ __launch_bounds__(256) void gemm_bf16_kernel(
    const unsigned short* __restrict__ A, const unsigned short* __restrict__ B,
    const float* __restrict__ scale, const float* __restrict__ bias,
    float* __restrict__ out, int T, int K, int N) {
  __shared__ __align__(16) unsigned short lsA[BM * BK];
  __shared__ __align__(16) unsigned short lsB[BN * BK];

  const int nbn = N / BN;
  const int nwg = (T / BM) * nbn;
  const int q = nwg >> 3, r = nwg & 7;
  const int xcd = blockIdx.x & 7, off = blockIdx.x >> 3;
  const int swz = (xcd < r ? xcd * (q + 1) : r * (q + 1) + (xcd - r) * q) + off;
  const int bm = (swz / nbn) * BM;
  const int bn = (swz % nbn) * BN;

  const int tid = threadIdx.x;
  const int wave = tid >> 6, lane = tid & 63;
  const int wm = (wave >> 1) * 64, wn = (wave & 1) * 64;

  f32x4 acc[4][4] = {};

  const int srow = (wave << 3) + (lane >> 3);
  const int scolb = (lane & 7) * 16;
  const size_t Kb = (size_t)K * 2;
  const char* gA = (const char*)A + (size_t)bm * Kb + scolb;
  const char* gB = (const char*)B + (size_t)bn * Kb + scolb;
  char* laddrA = (char*)lsA + wave * 1024;
  char* laddrB = (char*)lsB + wave * 1024;

  for (int k0 = 0; k0 < K; k0 += BK) {
    const char* pa = gA + (size_t)k0 * 2;
    const char* pb = gB + (size_t)k0 * 2;
#pragma unroll
    for (int s = 0; s < 4; ++s) {
      int row = s * 32 + srow;
      gload_lds16(pa + (size_t)row * Kb, laddrA + s * 4096);
      gload_lds16(pb + (size_t)row * Kb, laddrB + s * 4096);
    }
    __syncthreads();

    const int arow2 = wm + (lane & 15);
    const int brow2 = wn + (lane & 15);
#pragma unroll
    for (int kk = 0; kk < BK; kk += 32) {
      const int kcol = kk + ((lane >> 4) << 3);
      bf16x8 af[4], bfr[4];
#pragma unroll
      for (int i = 0; i < 4; ++i)
        af[i] = *(const bf16x8*)(lsA + (size_t)(arow2 + i * 16) * BK + kcol);
#pragma unroll
      for (int i = 0; i < 4; ++i)
        bfr[i] = *(const bf16x8*)(lsB + (size_t)(brow2 + i * 16) * BK + kcol);
#pragma unroll
      for (int mi = 0; mi < 4; ++mi)
#pragma unroll
        for (int ni = 0; ni < 4; ++ni)
          acc[mi][ni] = __builtin_amdgcn_mfma_f32_16x16x32_bf16(
              af[mi], bfr[ni], acc[mi][ni], 0, 0, 0);
    }
    __syncthreads();
  }

  const int ccol = bn + wn + (lane & 15);
  const int crow0 = bm + wm + ((lane >> 4) << 2);
#pragma unroll
  for (int ni = 0; ni < 4; ++ni) {
    const int o = ccol + ni * 16;
    const float sc = scale[o], bi = bias[o];
#pragma unroll
    for (int mi = 0; mi < 4; ++mi) {
#pragma unroll
      for (int rr = 0; rr < 4; ++rr) {
        const int t2 = crow0 + mi * 16 + rr;
        out[(size_t)t2 * N + o] = acc[mi][ni][rr] * sc + bi;
      }
    }
  }
}

// ---------------- naive fallback ----------------

__global__ void naive_kernel(const float* __restrict__ X, const int* __restrict__ Wq,
                             const float* __restrict__ sc, const float* __restrict__ bs,
                             float* __restrict__ out, int T, int K, int N) {
  __shared__ float xt[16][16];
  __shared__ float wt[16][17];
  const int tx = threadIdx.x & 15, ty = threadIdx.x >> 4;
  const int t = blockIdx.y * 16 + ty, o = blockIdx.x * 16 + tx;
  float acc = 0.f;
  for (int k0 = 0; k0 < K; k0 += 16) {
    xt[ty][tx] = X[(size_t)t * K + k0 + tx];
    wt[ty][tx] = dec_e4m3(Wq[(size_t)(blockIdx.x * 16 + ty) * K + k0 + tx]);
    __syncthreads();
#pragma unroll
    for (int kk = 0; kk < 16; ++kk) acc += xt[ty][kk] * wt[tx][kk];
    __syncthreads();
  }
  out[(size_t)t * N + o] = acc * sc[o] + bs[o];
}

extern "C" void kernel_launch(void* const* d_in, const int* in_sizes, int n_in,
                              void* d_out, int out_size, void* d_ws, size_t ws_size,
                              hipStream_t stream) {
  const float* x  = (const float*)d_in[0];
  const int*   wq = (const int*)d_in[1];
  const float* sc = (const float*)d_in[2];
  const float* bi = (const float*)d_in[3];
  float* out = (float*)d_out;

  const int DOUT = in_sizes[2];
  const int DIN  = in_sizes[1] / DOUT;
  const int T    = in_sizes[0] / DIN;

  const size_t need = ((size_t)T * DIN + (size_t)DOUT * DIN) * 2;
  const bool ok256 = (T % 256 == 0) && (DOUT % 256 == 0) && (DIN % 256 == 0);
  const bool ok128 = (T % BM == 0) && (DOUT % BN == 0) && (DIN % BK == 0);

  if (ws_size >= need && (ok256 || ok128)) {
    unsigned short* xb = (unsigned short*)d_ws;
    unsigned short* wb = xb + (size_t)T * DIN;
    const int nx8 = (int)((size_t)T * DIN / 8);
    const int nw8 = (int)((size_t)DOUT * DIN / 8);
    cvt_x_kernel<<<(nx8 + 255) / 256, 256, 0, stream>>>(x, xb, nx8);
    dec_w_kernel<<<(nw8 + 255) / 256, 256, 0, stream>>>(wq, wb, nw8);
    if (ok256) {
      const int nbm = T >> 8, nbn = DOUT >> 8;
      const bool okchain = ((nbm & 3) == 0) && ((nbn & 7) == 0);
      const int grid = okchain ? (nbm >> 2) * nbn : nbm * nbn;
      gemm256_kernel<<<grid, 512, 131072, stream>>>(xb, wb, sc, bi, out, T, DIN, DOUT);
    } else {
      dim3 grid((T / BM) * (DOUT / BN));
      gemm_bf16_kernel<<<grid, 256, 0, stream>>>(xb, wb, sc, bi, out, T, DIN, DOUT);
    }
  } else {
    dim3 g(DOUT / 16, T / 16);
    naive_kernel<<<g, 256, 0, stream>>>(x, wq, sc, bi, out, T, DIN, DOUT);
  }
}

// Round 15
// 513.711 us; speedup vs baseline: 1.0817x; 1.0817x over previous
//
#include <hip/hip_runtime.h>

using short8 = __attribute__((ext_vector_type(8))) short;
using bf16x8 = __attribute__((ext_vector_type(8))) __bf16;
using f32x4  = __attribute__((ext_vector_type(4))) float;

__device__ __forceinline__ void gload_lds16(const void* g, void* l) {
  __builtin_amdgcn_global_load_lds(
      (const __attribute__((address_space(1))) void*)g,
      (__attribute__((address_space(3))) void*)l, 16, 0, 0);
}

// ---------------- prepass: decode/convert ----------------

__device__ __forceinline__ float dec_e4m3(int b) {
  int e = (b >> 3) & 15;
  int m = b & 7;
  if (e == 15 && m == 7) m = 6;  // NaN pattern -> 448 per reference
  float v;
  if (e) v = (1.0f + (float)m * 0.125f) * __uint_as_float((unsigned)(e + 120) << 23);
  else   v = (float)m * 0.001953125f;  // m * 2^-9
  return (b & 0x80) ? -v : v;
}

__global__ void dec_w_kernel(const int* __restrict__ wq,
                             unsigned short* __restrict__ wb, int n8) {
  int i = blockIdx.x * blockDim.x + threadIdx.x;
  if (i >= n8) return;
  const int4* p = (const int4*)wq + (size_t)i * 2;
  int4 a = p[0], b4 = p[1];
  int bv[8] = {a.x, a.y, a.z, a.w, b4.x, b4.y, b4.z, b4.w};
  short8 r;
#pragma unroll
  for (int j = 0; j < 8; ++j) {
    float f = dec_e4m3(bv[j]);
    r[j] = (short)(__float_as_uint(f) >> 16);  // exact (<=3 mantissa bits)
  }
  *(short8*)(wb + (size_t)i * 8) = r;
}

__global__ void cvt_x_kernel(const float* __restrict__ x,
                             unsigned short* __restrict__ xb, int n8) {
  int i = blockIdx.x * blockDim.x + threadIdx.x;
  if (i >= n8) return;
  const float4* p = (const float4*)x + (size_t)i * 2;
  float4 a = p[0], b4 = p[1];
  float v[8] = {a.x, a.y, a.z, a.w, b4.x, b4.y, b4.z, b4.w};
  short8 r;
#pragma unroll
  for (int j = 0; j < 8; ++j) {
    unsigned u = __float_as_uint(v[j]);
    u += 0x7FFFu + ((u >> 16) & 1u);  // RNE
    r[j] = (short)(u >> 16);
  }
  *(short8*)(xb + (size_t)i * 8) = r;
}

// ------- 256x256 GEMM: 1-barrier phases, compiler-scoreboarded waits ------
// C[t,o] = scale[o] * sum_k A[t,k]*B[o,k] + bias[o]
// A: [T][K] bf16, B: [N][K] bf16 (row-major, B^T GEMM). 512 thr = 8 waves
// (2M x 4N), per-wave C 128x64 = acc[8][4] 16x16 f32x4. LDS 128KB dbuf.
// XOR swizzle byte^=((row&7)<<4) via pre-swizzled global source (0-conflict).
// Phase: {MFMA(prio1), compiler-inserted fine-grained lgkmcnt for last
// phase's prefetch; sched_barrier (pins MFMAs above vmcnt asm -- rule #18);
// stage; [VM6 after MFMA only]; prefetch ds_reads; s_barrier}.
// Session lessons encoded: no reads/waits/branches at phase head (R9/R10/
// R12); 8-phase granularity is the optimum (R14 merged phases regressed).
// Chains of 4 bm tiles; XCD-column locality map; NT-store epilogue.
// FINAL (= R13, session best: total 516us, GEMM 478us, 1.15 PF, MfmaUtil 53.5%).

#define NOPV ((void)0)
#define VM6 asm volatile("s_waitcnt vmcnt(6)" ::: "memory")
#define VM0 asm volatile("s_waitcnt vmcnt(0)" ::: "memory")

#define STAGE_A(GP, LBUF, KT, J) do { \
    const char* _g = (GP) + (size_t)(KT) * 128u; \
    gload_lds16(_g + (size_t)((J) * 64) * Kb, (LBUF) + ((J) * 64) * 128 + tdA); \
    gload_lds16(_g + (size_t)(128 + (J) * 64) * Kb, (LBUF) + (128 + (J) * 64) * 128 + tdA); \
  } while (0)

#define STAGE_B(GP, LBUF, KT, J) do { \
    const char* _g = (GP) + (size_t)(KT) * 128u; \
    gload_lds16(_g + (size_t)((J) * 32) * Kb, (LBUF) + ((J) * 32) * 128 + tdB); \
    gload_lds16(_g + (size_t)(128 + (J) * 32) * Kb, (LBUF) + (128 + (J) * 32) * 128 + tdB); \
  } while (0)

// A-quadrant QM from LDS byte-base LB: 8 x ds_read_b128 (0-conflict layout)
#define RD_A(DST, LB, QM) do { \
    _Pragma("unroll") \
    for (int mi = 0; mi < 4; ++mi) { \
      const char* _b = lds + (LB) + (size_t)(arow + (QM) * 64 + mi * 16) * 128; \
      (DST)[mi * 2 + 0] = *(const bf16x8*)(_b + fo0); \
      (DST)[mi * 2 + 1] = *(const bf16x8*)(_b + fo1); \
    } \
  } while (0)

// B-half QN from LDS byte-base LB: 4 x ds_read_b128
#define RD_B(DST, LB, QN) do { \
    _Pragma("unroll") \
    for (int ni = 0; ni < 2; ++ni) { \
      const char* _b = lds + (LB) + 32768 + (size_t)(brow + ((QN) * 2 + ni) * 16) * 128; \
      (DST)[ni * 2 + 0] = *(const bf16x8*)(_b + fo0); \
      (DST)[ni * 2 + 1] = *(const bf16x8*)(_b + fo1); \
    } \
  } while (0)

// Phase: NO hand lgkm wait -- compiler scoreboards the register deps and
// weaves decremental lgkmcnt(N) between MFMAs (G7/m97 behavior).
#define PH(AB, BB, QM, QN, STBLK, VMBLK, PFBLK) do { \
    __builtin_amdgcn_s_setprio(1); \
    _Pragma("unroll") \
    for (int mi = 0; mi < 4; ++mi) \
      _Pragma("unroll") \
      for (int ni = 0; ni < 2; ++ni) \
        _Pragma("unroll") \
        for (int ks = 0; ks < 2; ++ks) \
          acc[(QM) * 4 + mi][(QN) * 2 + ni] = __builtin_amdgcn_mfma_f32_16x16x32_bf16( \
              (AB)[mi * 2 + ks], (BB)[ni * 2 + ks], acc[(QM) * 4 + mi][(QN) * 2 + ni], 0, 0, 0); \
    __builtin_amdgcn_s_setprio(0); \
    __builtin_amdgcn_sched_barrier(0); \
    STBLK; \
    VMBLK; \
    PFBLK; \
    __builtin_amdgcn_s_barrier(); \
  } while (0)

__global__ __launch_bounds__(512, 2) void gemm256_kernel(
    const unsigned short* __restrict__ A, const unsigned short* __restrict__ B,
    const float* __restrict__ scale, const float* __restrict__ bias,
    float* __restrict__ out, int T, int K, int N) {
  extern __shared__ char lds[];
  char* const lA0 = lds;
  char* const lB0 = lds + 32768;
  char* const lA1 = lds + 65536;
  char* const lB1 = lds + 98304;
  const int L0A = 0, L0B = 0, L1A = 65536, L1B = 65536;  // RD_* add +32768 for B

  const int nbn = N >> 8;
  const int nbm = T >> 8;
  int bm, bn, CH;
  if (((nbm & 3) == 0) && ((nbn & 7) == 0) &&
      (int)gridDim.x == (nbm >> 2) * nbn) {
    const int xcd = blockIdx.x & 7, off = blockIdx.x >> 3;
    const int cpx = nbn >> 3;
    const int col = xcd * cpx + (off % cpx);
    const int ci  = off / cpx;
    bm = (ci * 4) << 8;
    bn = col << 8;
    CH = 4;
  } else {
    const int nwg = nbm * nbn;
    const int q = nwg >> 3, r = nwg & 7;
    const int xcd = blockIdx.x & 7, off = blockIdx.x >> 3;
    const int swz = (xcd < r ? xcd * (q + 1) : r * (q + 1) + (xcd - r) * q) + off;
    bm = (swz / nbn) << 8;
    bn = (swz % nbn) << 8;
    CH = 1;
  }

  const int tid = threadIdx.x;
  const int wave = tid >> 6, lane = tid & 63;
  const int wm = wave >> 2, wn = wave & 3;
  const int nt = K >> 6;           // K-tiles (BK=64); requires nt even >= 4
  const size_t Kb = (size_t)K * 2;

  // staging (pre-swizzled global source, linear LDS dest) — R2-verified
  const int trow = tid >> 3;
  const int gcol = ((tid & 7) * 16) ^ (((tid >> 3) & 7) << 4);
  const int bmap = ((tid & 256) ? 64 : 0) + ((tid >> 6) & 3) * 8 + ((tid >> 3) & 7);
  const char* gAb = (const char*)A + (size_t)(bm + trow) * Kb + gcol;
  const char* gBb = (const char*)B + (size_t)(bn + bmap) * Kb + gcol;
  const int tdA = tid * 16;
  const int tdB = bmap * 128 + (tid & 7) * 16;

  // fragment read offsets (0-conflict, R2)
  const int g16 = lane >> 4, l8 = lane & 7;
  const int fo0 = ((g16 ^ l8) << 4);
  const int fo1 = fo0 ^ 64;
  const int arow = wm * 128 + (lane & 15);
  const int brow = wn * 64 + (lane & 15);

  // epilogue addressing + hoisted scale/bias (bn fixed for whole chain)
  const int ccol = bn + wn * 64 + (lane & 15);
  int crow = bm + wm * 128 + ((lane >> 4) << 2);
  float scv[4], biv[4];
#pragma unroll
  for (int ni = 0; ni < 4; ++ni) {
    scv[ni] = scale[ccol + ni * 16];
    biv[ni] = bias[ccol + ni * 16];
  }

  f32x4 acc[8][4] = {};
  bf16x8 aE[8], aO[8], b0a[4], b0b[4], b1[4];

  for (int ch = 0; ch < CH; ++ch) {
    const bool more = (ch + 1 < CH);
    const char* gAn = gAb + (size_t)256 * Kb;

    if (ch == 0) {
      // cold prologue: tile0 full (8), tile1 {Ah0,Bh0,Bh1} (6); VM6 -> tile0 ready
      STAGE_A(gAb, lA0, 0, 0);
      STAGE_B(gBb, lB0, 0, 0);
      STAGE_B(gBb, lB0, 0, 1);
      STAGE_A(gAb, lA0, 0, 1);
      STAGE_A(gAb, lA1, 1, 0);
      STAGE_B(gBb, lB1, 1, 0);
      STAGE_B(gBb, lB1, 1, 1);
      VM6;
      __builtin_amdgcn_s_barrier();
      RD_A(aE, L0A, 0);
      RD_B(b0a, L0B, 0);
    }

    int t = 0;
    for (; t + 3 < nt; t += 2) {
      // tile t (buf0)
      PH(aE, b0a, 0, 0, STAGE_A(gAb, lA1, t + 1, 1), NOPV, RD_B(b1, L0B, 1));
      PH(aE, b1,  0, 1, STAGE_A(gAb, lA0, t + 2, 0), NOPV, RD_A(aO, L0A, 1));
      PH(aO, b1,  1, 1, STAGE_B(gBb, lB0, t + 2, 0), NOPV, NOPV);
      PH(aO, b0a, 1, 0, STAGE_B(gBb, lB0, t + 2, 1), VM6,
         { RD_A(aE, L1A, 0); RD_B(b0b, L1B, 0); });
      // tile t+1 (buf1)
      PH(aE, b0b, 0, 0, STAGE_A(gAb, lA0, t + 2, 1), NOPV, RD_B(b1, L1B, 1));
      PH(aE, b1,  0, 1, STAGE_A(gAb, lA1, t + 3, 0), NOPV, RD_A(aO, L1A, 1));
      PH(aO, b1,  1, 1, STAGE_B(gBb, lB1, t + 3, 0), NOPV, NOPV);
      PH(aO, b0b, 1, 0, STAGE_B(gBb, lB1, t + 3, 1), VM6,
         { RD_A(aE, L0A, 0); RD_B(b0a, L0B, 0); });
    }
    // tail: tile nt-2 (buf0) — VM0 before the cross-buffer prefetch
    PH(aE, b0a, 0, 0, STAGE_A(gAb, lA1, t + 1, 1), NOPV, RD_B(b1, L0B, 1));
    PH(aE, b1,  0, 1, NOPV, NOPV, RD_A(aO, L0A, 1));
    PH(aO, b1,  1, 1, NOPV, NOPV, NOPV);
    PH(aO, b0a, 1, 0, NOPV, VM0, { RD_A(aE, L1A, 0); RD_B(b0b, L1B, 0); });
    // tail: tile nt-1 (buf1) — weave next-chain k0 stages into buf0
    PH(aE, b0b, 0, 0, { if (more) STAGE_A(gAn, lA0, 0, 0); }, NOPV, RD_B(b1, L1B, 1));
    PH(aE, b1,  0, 1, { if (more) STAGE_B(gBb, lB0, 0, 0); }, NOPV, RD_A(aO, L1A, 1));
    PH(aO, b1,  1, 1, { if (more) STAGE_B(gBb, lB0, 0, 1); }, NOPV, NOPV);
    PH(aO, b0b, 1, 0, { if (more) STAGE_A(gAn, lA0, 0, 1); }, NOPV, NOPV);

    // epilogue: NT stores (C/D: col=lane&15, row=(lane>>4)*4+reg)
#pragma unroll
    for (int ni = 0; ni < 4; ++ni) {
      const int o = ccol + ni * 16;
#pragma unroll
      for (int mi = 0; mi < 8; ++mi) {
#pragma unroll
        for (int rr = 0; rr < 4; ++rr) {
          __builtin_nontemporal_store(acc[mi][ni][rr] * scv[ni] + biv[ni],
                                      &out[(size_t)(crow + mi * 16 + rr) * N + o]);
        }
      }
    }

    if (more) {
#pragma unroll
      for (int mi = 0; mi < 8; ++mi)
#pragma unroll
        for (int ni = 0; ni < 4; ++ni)
          acc[mi][ni] = (f32x4){0.f, 0.f, 0.f, 0.f};
      // stage next tile's k1; VM6 -> k0 landed; prefetch first operands
      STAGE_A(gAn, lA1, 1, 0);
      STAGE_B(gBb, lB1, 1, 0);
      STAGE_B(gBb, lB1, 1, 1);
      VM6;
      __builtin_amdgcn_s_barrier();
      RD_A(aE, L0A, 0);
      RD_B(b0a, L0B, 0);
      gAb = gAn;
      crow += 256;
    }
  }
}

// ---------------- m97 128x128 fallback ----------------

#define BM 128
#define BN 128
#define BK 64

__global__ __launch_bounds__(256) void gemm_bf16_kernel(
    const unsigned short* __restrict__ A, const unsigned short* __restrict__ B,
    const float* __restrict__ scale, const float* __restrict__ bias,
    float* __restrict__ out, int T, int K, int N) {
  __shared__ __align__(16) unsigned short lsA[BM * BK];
  __shared__ __align__(16) unsigned short lsB[BN * BK];

  const int nbn = N / BN;
  const int nwg = (T / BM) * nbn;
  const int q = nwg >> 3, r = nwg & 7;
  const int xcd = blockIdx.x & 7, off = blockIdx.x >> 3;
  const int swz = (xcd < r ? xcd * (q + 1) : r * (q + 1) + (xcd - r) * q) + off;
  const int bm = (swz / nbn) * BM;
  const int bn = (swz % nbn) * BN;

  const int tid = threadIdx.x;
  const int wave = tid >> 6, lane = tid & 63;
  const int wm = (wave >> 1) * 64, wn = (wave & 1) * 64;

  f32x4 acc[4][4] = {};

  const int srow = (wave << 3) + (lane >> 3);
  const int scolb = (lane & 7) * 16;
  const size_t Kb = (size_t)K * 2;
  const char* gA = (const char*)A + (size_t)bm * Kb + scolb;
  const char* gB = (const char*)B + (size_t)bn * Kb + scolb;
  char* laddrA = (char*)lsA + wave * 1024;
  char* laddrB = (char*)lsB + wave * 1024;

  for (int k0 = 0; k0 < K; k0 += BK) {
    const char* pa = gA + (size_t)k0 * 2;
    const char* pb = gB + (size_t)k0 * 2;
#pragma unroll
    for (int s = 0; s < 4; ++s) {
      int row = s * 32 + srow;
      gload_lds16(pa + (size_t)row * Kb, laddrA + s * 4096);
      gload_lds16(pb + (size_t)row * Kb, laddrB + s * 4096);
    }
    __syncthreads();

    const int arow2 = wm + (lane & 15);
    const int brow2 = wn + (lane & 15);
#pragma unroll
    for (int kk = 0; kk < BK; kk += 32) {
      const int kcol = kk + ((lane >> 4) << 3);
      bf16x8 af[4], bfr[4];
#pragma unroll
      for (int i = 0; i < 4; ++i)
        af[i] = *(const bf16x8*)(lsA + (size_t)(arow2 + i * 16) * BK + kcol);
#pragma unroll
      for (int i = 0; i < 4; ++i)
        bfr[i] = *(const bf16x8*)(lsB + (size_t)(brow2 + i * 16) * BK + kcol);
#pragma unroll
      for (int mi = 0; mi < 4; ++mi)
#pragma unroll
        for (int ni = 0; ni < 4; ++ni)
          acc[mi][ni] = __builtin_amdgcn_mfma_f32_16x16x32_bf16(
              af[mi], bfr[ni], acc[mi][ni], 0, 0, 0);
    }
    __syncthreads();
  }

  const int ccol = bn + wn + (lane & 15);
  const int crow0 = bm + wm + ((lane >> 4) << 2);
#pragma unroll
  for (int ni = 0; ni < 4; ++ni) {
    const int o = ccol + ni * 16;
    const float sc = scale[o], bi = bias[o];
#pragma unroll
    for (int mi = 0; mi < 4; ++mi) {
#pragma unroll
      for (int rr = 0; rr < 4; ++rr) {
        const int t2 = crow0 + mi * 16 + rr;
        out[(size_t)t2 * N + o] = acc[mi][ni][rr] * sc + bi;
      }
    }
  }
}

// ---------------- naive fallback ----------------

__global__ void naive_kernel(const float* __restrict__ X, const int* __restrict__ Wq,
                             const float* __restrict__ sc, const float* __restrict__ bs,
                             float* __restrict__ out, int T, int K, int N) {
  __shared__ float xt[16][16];
  __shared__ float wt[16][17];
  const int tx = threadIdx.x & 15, ty = threadIdx.x >> 4;
  const int t = blockIdx.y * 16 + ty, o = blockIdx.x * 16 + tx;
  float acc = 0.f;
  for (int k0 = 0; k0 < K; k0 += 16) {
    xt[ty][tx] = X[(size_t)t * K + k0 + tx];
    wt[ty][tx] = dec_e4m3(Wq[(size_t)(blockIdx.x * 16 + ty) * K + k0 + tx]);
    __syncthreads();
#pragma unroll
    for (int kk = 0; kk < 16; ++kk) acc += xt[ty][kk] * wt[tx][kk];
    __syncthreads();
  }
  out[(size_t)t * N + o] = acc * sc[o] + bs[o];
}

extern "C" void kernel_launch(void* const* d_in, const int* in_sizes, int n_in,
                              void* d_out, int out_size, void* d_ws, size_t ws_size,
                              hipStream_t stream) {
  const float* x  = (const float*)d_in[0];
  const int*   wq = (const int*)d_in[1];
  const float* sc = (const float*)d_in[2];
  const float* bi = (const float*)d_in[3];
  float* out = (float*)d_out;

  const int DOUT = in_sizes[2];
  const int DIN  = in_sizes[1] / DOUT;
  const int T    = in_sizes[0] / DIN;

  const size_t need = ((size_t)T * DIN + (size_t)DOUT * DIN) * 2;
  const bool ok256 = (T % 256 == 0) && (DOUT % 256 == 0) && (DIN % 256 == 0);
  const bool ok128 = (T % BM == 0) && (DOUT % BN == 0) && (DIN % BK == 0);

  if (ws_size >= need && (ok256 || ok128)) {
    unsigned short* xb = (unsigned short*)d_ws;
    unsigned short* wb = xb + (size_t)T * DIN;
    const int nx8 = (int)((size_t)T * DIN / 8);
    const int nw8 = (int)((size_t)DOUT * DIN / 8);
    cvt_x_kernel<<<(nx8 + 255) / 256, 256, 0, stream>>>(x, xb, nx8);
    dec_w_kernel<<<(nw8 + 255) / 256, 256, 0, stream>>>(wq, wb, nw8);
    if (ok256) {
      const int nbm = T >> 8, nbn = DOUT >> 8;
      const bool okchain = ((nbm & 3) == 0) && ((nbn & 7) == 0);
      const int grid = okchain ? (nbm >> 2) * nbn : nbm * nbn;
      gemm256_kernel<<<grid, 512, 131072, stream>>>(xb, wb, sc, bi, out, T, DIN, DOUT);
    } else {
      dim3 grid((T / BM) * (DOUT / BN));
      gemm_bf16_kernel<<<grid, 256, 0, stream>>>(xb, wb, sc, bi, out, T, DIN, DOUT);
    }
  } else {
    dim3 g(DOUT / 16, T / 16);
    naive_kernel<<<g, 256, 0, stream>>>(x, wq, sc, bi, out, T, DIN, DOUT);
  }
}